// Round 6
// baseline (260.493 us; speedup 1.0000x reference)
//
#include <hip/hip_runtime.h>

// SelfAttention: GN -> 1x1 QKV -> softmax attention (HW=1024) -> 1x1 proj + residual
// B=16, C=512, HW=1024, GROUPS=32, EPS=1e-5, scale=C^-0.5
//
// Round 6: barrier-free wave-autonomous GEMM *with explicit waitcnt ordering* (R5 failed
// because the compiler does NOT model global_load_lds->ds_read RAW through LDS):
//   - RAW: s_waitcnt vmcnt(8) before reading tile it's frags (tile it+1's 8 loads stay
//          in flight); vmcnt(0) on the peeled last iteration.
//   - WAR: s_waitcnt lgkmcnt(0) after frag ds_reads (frags in VGPRs -> buffer dead),
//          THEN issue the depth-2 prefetch into that same buffer. 2 buffers suffice.
// No __syncthreads in the K-loop; waves de-lockstep. LDS 64 KB -> 2 blocks/CU.
// Layouts (all [free][K]):
//   xnT [b][hw][c], qkT [b][hw][q|k], v [b][c][hw], S/P [b][i][j], aoutT [b][hw][c]

typedef _Float16 f16;
typedef _Float16 f16x8 __attribute__((ext_vector_type(8)));
typedef _Float16 f16x4 __attribute__((ext_vector_type(4)));
typedef float fx4 __attribute__((ext_vector_type(4)));

// s_waitcnt simm16 encodings (gfx9): vmcnt[3:0] | expcnt[6:4] | lgkmcnt[11:8] | vmcnt[5:4]<<14
#define WAIT_VM8   0x0F78   // vmcnt(8),  expcnt/lgkmcnt unconstrained
#define WAIT_VM0   0x0F70   // vmcnt(0)
#define WAIT_LGKM0 0xC07F   // lgkmcnt(0), vmcnt/expcnt unconstrained

__device__ __forceinline__ void gload16(const f16* g, f16* l) {
    __builtin_amdgcn_global_load_lds((const __attribute__((address_space(1))) void*)g,
                                     (__attribute__((address_space(3))) void*)l, 16, 0, 0);
}

// ---------------- weight convert: fp32 -> f16, n4 float4 chunks ----------------
__global__ __launch_bounds__(256)
void wconv_kernel(const float* __restrict__ w, f16* __restrict__ o, int n4)
{
    int i = blockIdx.x * 256 + threadIdx.x;
    if (i < n4) {
        float4 v = *(const float4*)(w + i * 4);
        f16x4 h;
        h[0] = (f16)v.x; h[1] = (f16)v.y; h[2] = (f16)v.z; h[3] = (f16)v.w;
        *(f16x4*)(o + i * 4) = h;
    }
}

// ---------------- GroupNorm: x fp32 [16][512][1024] -> xnT f16 [16][1024][512] ----------------
// Single global read: x kept in registers (16 float4/thread) across stats + normalize.
__global__ __launch_bounds__(256)
void groupnorm_kernel(const float* __restrict__ x, const float* __restrict__ gamma,
                      const float* __restrict__ beta, f16* __restrict__ xnT)
{
    __shared__ float red[256], red2[256];
    __shared__ float mu_s, rs_s;
    __shared__ __align__(16) f16 T[16][1040];  // [ch][hw], padded
    const int blk = blockIdx.x;                // b*32 + g
    const int b = blk >> 5, g = blk & 31;
    const long base = (long)blk * 16384;       // 16 ch * 1024 hw
    const int tid = threadIdx.x;
    const float4* xv = (const float4*)(x + base);

    float4 xr[16];
    float s = 0.f, s2 = 0.f;
#pragma unroll
    for (int i = 0; i < 16; i++) {
        float4 v = xv[tid + i * 256];          // float4 #(tid) of channel i
        xr[i] = v;
        s  += v.x + v.y + v.z + v.w;
        s2 += v.x * v.x + v.y * v.y + v.z * v.z + v.w * v.w;
    }
    red[tid] = s; red2[tid] = s2;
    __syncthreads();
    for (int off = 128; off > 0; off >>= 1) {
        if (tid < off) { red[tid] += red[tid + off]; red2[tid] += red2[tid + off]; }
        __syncthreads();
    }
    if (tid == 0) {
        float mu = red[0] * (1.f / 16384.f);
        float var = red2[0] * (1.f / 16384.f) - mu * mu;
        mu_s = mu;
        rs_s = rsqrtf(var + 1e-5f);
    }
    __syncthreads();
    const float mu = mu_s, rs = rs_s;

#pragma unroll
    for (int i = 0; i < 16; i++) {             // channel i, pos4 = tid
        float gm = gamma[g * 16 + i] * rs;
        float bt = beta[g * 16 + i] - mu * gm;
        float4 v = xr[i];
        f16x4 o;
        o[0] = (f16)(v.x * gm + bt);
        o[1] = (f16)(v.y * gm + bt);
        o[2] = (f16)(v.z * gm + bt);
        o[3] = (f16)(v.w * gm + bt);
        *(f16x4*)&T[i][tid * 4] = o;
    }
    __syncthreads();
    // transposed write: xnT[b][hw][g*16 + 0..15], 16B chunks
#pragma unroll
    for (int i = 0; i < 8; i++) {
        int idx = tid + i * 256;               // 0..2047
        int hw = idx >> 1;
        int half8 = (idx & 1) * 8;
        f16x8 o;
#pragma unroll
        for (int j = 0; j < 8; j++) o[j] = T[half8 + j][hw];
        long dst = ((long)b * 1024 + hw) * 512 + g * 16 + half8;
        *(f16x8*)(xnT + dst) = o;
    }
}

// ---------------- Row softmax over j: S f16 [16][1024][1024], one wave per row ----------------
__global__ __launch_bounds__(256)
void softmax_kernel(f16* __restrict__ S)
{
    const int wid = blockIdx.x * 4 + (threadIdx.x >> 6);
    const int lane = threadIdx.x & 63;
    f16* p = S + (long)wid * 1024 + lane * 16;
    f16x8 h0 = *(const f16x8*)p;
    f16x8 h1 = *(const f16x8*)(p + 8);
    float v[16];
#pragma unroll
    for (int i = 0; i < 8; i++) { v[i] = (float)h0[i]; v[8 + i] = (float)h1[i]; }
    float mx = v[0];
#pragma unroll
    for (int i = 1; i < 16; i++) mx = fmaxf(mx, v[i]);
    for (int off = 32; off > 0; off >>= 1) mx = fmaxf(mx, __shfl_xor(mx, off, 64));
    float sum = 0.f;
#pragma unroll
    for (int i = 0; i < 16; i++) { v[i] = __expf(v[i] - mx); sum += v[i]; }
    for (int off = 32; off > 0; off >>= 1) sum += __shfl_xor(sum, off, 64);
    const float inv = 1.f / sum;
#pragma unroll
    for (int i = 0; i < 8; i++) { h0[i] = (f16)(v[i] * inv); h1[i] = (f16)(v[8 + i] * inv); }
    *(f16x8*)p = h0;
    *(f16x8*)(p + 8) = h1;
}

// ---------------- barrier-free 128x128 GEMM (4 autonomous 64x64 wave-tiles) -------------------
// A stored [M][K] f16 (lda), B stored [N][K] f16 (ldb).
// Wave-private LDS: [wave][A/B][buf 0/1][64x32], XOR chunk swizzle (chunk' = chunk^(row&3)).
// Explicit waitcnt ordering (see header comment).
// MODE 0: f16 out C[m][n] ld=N, batch stride sCb, *alpha.
// MODE 1: QKV split: n0<1024 -> qkT[b][m][n] (ld 1024); n0>=1024 -> v[b][n-1024][m]; bias[n].
// MODE 2: fp32 out [m][n] ld=N + bias[m] + resid, batch stride sCb.
template<int MODE>
__global__ __launch_bounds__(256)
void gemm_kernel(const f16* __restrict__ Ap, const f16* __restrict__ Bp,
                 void* __restrict__ Cp, f16* __restrict__ C2p,
                 const float* __restrict__ bias, const float* __restrict__ resid,
                 float alpha, int M, int N, int K, int lda, int ldb,
                 long sAb, long sBb, long sCb)
{
    __shared__ __align__(16) f16 lds[4][2][2][2048];   // [wave][A/B][buf][64rows x 32k] = 64 KB

    const int b = blockIdx.z;
    const int m0 = blockIdx.y * 128, n0 = blockIdx.x * 128;
    const int tid = threadIdx.x;
    const int wave = tid >> 6, lane = tid & 63;
    const int quad = lane >> 4, l15 = lane & 15;
    const int wm = (wave >> 1) * 64, wn = (wave & 1) * 64;
    const int chunkoff = (quad ^ (l15 & 3)) * 8;       // loop-invariant frag chunk

    const int si = lane >> 2;                           // row within 16-row staging instr
    const int sj = lane & 3;                            // chunk slot
    const int sjx = (sj ^ (si & 3)) * 8;                // lane-constant (rows advance by 16)

    const f16* Ag = Ap + (long)b * sAb + (long)(m0 + wm + si) * lda + sjx;
    const f16* Bg = Bp + (long)b * sBb + (long)(n0 + wn + si) * ldb + sjx;

    f16* ldsA = &lds[wave][0][0][0];
    f16* ldsB = &lds[wave][1][0][0];

    fx4 acc[4][4] = {};
    const int nIter = K >> 5;

#define STAGE(buf, kOff)                                                        \
    { _Pragma("unroll")                                                          \
      for (int s = 0; s < 4; s++) {                                              \
          gload16(Ag + (kOff) + (s * 16) * lda, ldsA + (buf) * 2048 + s * 512);  \
          gload16(Bg + (kOff) + (s * 16) * ldb, ldsB + (buf) * 2048 + s * 512);  \
      } }

    STAGE(0, 0)        // tile 0 -> buf 0   (8 loads)
    STAGE(1, 32)       // tile 1 -> buf 1   (8 loads)

    for (int it = 0; it < nIter - 1; ++it) {
        const int cur = it & 1;
        const f16* bA = ldsA + cur * 2048;
        const f16* bB = ldsB + cur * 2048;
        __builtin_amdgcn_s_waitcnt(WAIT_VM8);    // tile it's 8 loads landed (it+1's in flight)
        f16x8 af[4], bf[4];
#pragma unroll
        for (int t = 0; t < 4; t++) af[t] = *(const f16x8*)&bA[(t * 16 + l15) * 32 + chunkoff];
#pragma unroll
        for (int t = 0; t < 4; t++) bf[t] = *(const f16x8*)&bB[(t * 16 + l15) * 32 + chunkoff];
        __builtin_amdgcn_s_waitcnt(WAIT_LGKM0);  // frags in VGPRs -> buffer cur is dead
        if (it + 2 < nIter) { STAGE(cur, (it + 2) << 5) }   // depth-2 prefetch into buf cur
#pragma unroll
        for (int tm = 0; tm < 4; tm++)
#pragma unroll
            for (int tn = 0; tn < 4; tn++)
                acc[tm][tn] = __builtin_amdgcn_mfma_f32_16x16x32_f16(af[tm], bf[tn], acc[tm][tn], 0, 0, 0);
    }
    {   // peeled last iteration: drain everything
        const int cur = (nIter - 1) & 1;
        const f16* bA = ldsA + cur * 2048;
        const f16* bB = ldsB + cur * 2048;
        __builtin_amdgcn_s_waitcnt(WAIT_VM0);
        f16x8 af[4], bf[4];
#pragma unroll
        for (int t = 0; t < 4; t++) af[t] = *(const f16x8*)&bA[(t * 16 + l15) * 32 + chunkoff];
#pragma unroll
        for (int t = 0; t < 4; t++) bf[t] = *(const f16x8*)&bB[(t * 16 + l15) * 32 + chunkoff];
#pragma unroll
        for (int tm = 0; tm < 4; tm++)
#pragma unroll
            for (int tn = 0; tn < 4; tn++)
                acc[tm][tn] = __builtin_amdgcn_mfma_f32_16x16x32_f16(af[tm], bf[tn], acc[tm][tn], 0, 0, 0);
    }
#undef STAGE

    // ---- epilogue (wave-private, no sync needed): D[row=quad*4+r][col=l15] per 16x16 tile
    if (MODE == 1 && n0 >= 1024) {
        // v-part: write transposed to v[b][c][hw], vectorized f16x4 along hw(=m)
#pragma unroll
        for (int tm = 0; tm < 4; tm++)
#pragma unroll
        for (int tn = 0; tn < 4; tn++) {
            int gc = n0 + wn + tn * 16 + l15;
            int gr0 = m0 + wm + tm * 16 + quad * 4;
            float bs = bias[gc];
            f16x4 o;
#pragma unroll
            for (int r = 0; r < 4; r++) o[r] = (f16)(acc[tm][tn][r] + bs);
            *(f16x4*)(C2p + (long)b * 524288 + (long)(gc - 1024) * 1024 + gr0) = o;
        }
        return;
    }
#pragma unroll
    for (int tm = 0; tm < 4; tm++)
#pragma unroll
    for (int tn = 0; tn < 4; tn++) {
        int gc = n0 + wn + tn * 16 + l15;
#pragma unroll
        for (int r = 0; r < 4; r++) {
            int gr = m0 + wm + tm * 16 + quad * 4 + r;
            float v = acc[tm][tn][r] * alpha;
            if (MODE == 1) {
                v += bias[gc];
                ((f16*)Cp)[(long)b * 1048576 + (long)gr * 1024 + gc] = (f16)v;
            } else if (MODE == 2) {
                v += bias[gr];
                long idx = (long)b * sCb + (long)gr * N + gc;
                v += resid[idx];
                ((float*)Cp)[idx] = v;
            } else {
                ((f16*)Cp)[(long)b * sCb + (long)gr * N + gc] = (f16)v;
            }
        }
    }
}

extern "C" void kernel_launch(void* const* d_in, const int* in_sizes, int n_in,
                              void* d_out, int out_size, void* d_ws, size_t ws_size,
                              hipStream_t stream)
{
    const float* x      = (const float*)d_in[0];
    const float* gamma  = (const float*)d_in[1];
    const float* beta   = (const float*)d_in[2];
    const float* w_qkv  = (const float*)d_in[3];
    const float* b_qkv  = (const float*)d_in[4];
    const float* w_proj = (const float*)d_in[5];
    const float* b_proj = (const float*)d_in[6];
    float* out = (float*)d_out;

    char* ws = (char*)d_ws;
    f16* xnT   = (f16*)(ws);                 // 16 MB : [16][1024 hw][512 c]
    f16* qkT   = (f16*)(ws + (16L << 20));   // 32 MB : [16][1024 hw][1024 (q|k)]
    f16* vbuf  = (f16*)(ws + (48L << 20));   // 16 MB : [16][512 c][1024 hw]
    f16* S     = (f16*)(ws + (64L << 20));   // 32 MB : [16][1024 i][1024 j]
    f16* aoutT = (f16*)(ws + (96L << 20));   // 16 MB : [16][1024 hw][512 c]
    f16* wqkvh = S;                          // 1.5 MB; dead before scores writes S
    f16* wprjh = xnT;                        // 0.5 MB; written after QKV consumes xnT

    // 0) convert w_qkv fp32 -> f16 (into S region; scores overwrites later)
    wconv_kernel<<<768, 256, 0, stream>>>(w_qkv, wqkvh, 196608);

    // 1) GroupNorm -> xnT
    groupnorm_kernel<<<512, 256, 0, stream>>>(x, gamma, beta, xnT);

    // 2) QKV: C[m=hw][n=o] = xnT[hw][c] . w_qkv[o][c]; q,k -> qkT, v -> vbuf (transposed)
    gemm_kernel<1><<<dim3(12, 8, 16), 256, 0, stream>>>(
        xnT, wqkvh, qkT, vbuf, b_qkv, nullptr, 1.0f,
        1024, 1536, 512, /*lda*/512, /*ldb*/512,
        524288L, 0L, 0L);

    // 2b) convert w_proj fp32 -> f16 into xnT region (xnT dead after QKV)
    wconv_kernel<<<256, 256, 0, stream>>>(w_proj, wprjh, 65536);

    // 3) Scores: S[i][j] = scale * q[i][c] . k[j][c]
    gemm_kernel<0><<<dim3(8, 8, 16), 256, 0, stream>>>(
        qkT, qkT + 512, S, nullptr, nullptr, nullptr, 0.04419417382415922f,
        1024, 1024, 512, /*lda*/1024, /*ldb*/1024,
        1048576L, 1048576L, 1048576L);

    // 4) Softmax over j
    softmax_kernel<<<4096, 256, 0, stream>>>(S);

    // 5) PV: aoutT[i][c] = P[i][j] . v[c][j]
    gemm_kernel<0><<<dim3(4, 8, 16), 256, 0, stream>>>(
        S, vbuf, aoutT, nullptr, nullptr, nullptr, 1.0f,
        1024, 512, 1024, /*lda*/1024, /*ldb*/1024,
        1048576L, 524288L, 524288L);

    // 6) Proj: out[o][hw] = w_proj[o][c] . aoutT[hw][c] + b_proj[o] + x
    gemm_kernel<2><<<dim3(8, 4, 16), 256, 0, stream>>>(
        wprjh, aoutT, out, nullptr, b_proj, x, 1.0f,
        512, 1024, 512, /*lda*/512, /*ldb*/512,
        0L, 524288L, 524288L);
}